// Round 11
// baseline (306.589 us; speedup 1.0000x reference)
//
#include <hip/hip_runtime.h>
#include <hip/hip_bf16.h>
#include <cstdint>
#include <cstddef>

typedef short bf16x8 __attribute__((ext_vector_type(8)));   // 8 bf16 (4 VGPRs)
typedef float f32x4 __attribute__((ext_vector_type(4)));    // MFMA C/D

#define BCAP 4096          // entries per bucket (mean ~2046 at N=50k,E=800k)
#define NBK_MAX 512        // max buckets (N<=65536 -> <=512)
#define CHUNK 8192         // edges per scatter block
#define AGG_WAVES 8192

__device__ __forceinline__ void cvt2(unsigned int u, float& lo, float& hi) {
    union { unsigned int i; float f; } a, b;
    a.i = u << 16;
    b.i = u & 0xffff0000u;
    lo = a.f; hi = b.f;
}
__device__ __forceinline__ float bf2f(unsigned short s) {
    union { unsigned int i; float f; } c; c.i = ((unsigned int)s) << 16;
    return c.f;
}
__device__ __forceinline__ unsigned short f2bf(float f) {
    union { float f; unsigned int i; } c; c.f = f;
    unsigned int x = c.i;
    unsigned int r = (x + 0x7fffu + ((x >> 16) & 1u)) >> 16;
    return (unsigned short)r;
}

// single block: zero flag + bucket counters, detect dtype from 16KB sample
__global__ __launch_bounds__(256) void detect_k(const unsigned int* __restrict__ emb,
                                                int* __restrict__ flag,
                                                int* __restrict__ bucket_cnt, int nbk) {
    __shared__ unsigned int red[256];
    int t = threadIdx.x;
    for (int i = t; i < nbk; i += 256) bucket_cnt[i] = 0;
    unsigned int m = 0;
    #pragma unroll
    for (int i = 0; i < 16; ++i) {
        unsigned int u = emb[t + 256 * i];
        unsigned int lo = (u << 16) & 0x7fffffffu;
        m = m > lo ? m : lo;
    }
    red[t] = m; __syncthreads();
    for (int s = 128; s > 0; s >>= 1) {
        if (t < s) red[t] = red[t] > red[t + s] ? red[t] : red[t + s];
        __syncthreads();
    }
    if (t == 0) flag[0] = (red[0] > 0x4B000000u) ? 1 : 0;   // > 2^23 => fp32
}

__device__ __forceinline__ unsigned short in_bf16(const void* p, size_t i, int f) {
    if (f) return f2bf(((const float*)p)[i]);
    return ((const unsigned short*)p)[i];
}
__device__ __forceinline__ float in_f32(const void* p, size_t i, int f) {
    if (f) return ((const float*)p)[i];
    return bf2f(((const unsigned short*)p)[i]);
}

// merged pack: blocks 0..15 W1 frags, 16..31 W2 frags, 32 LN/bias params
__global__ __launch_bounds__(256) void pack_k(
    const void* __restrict__ W1, const void* __restrict__ W2,
    const void* b1, const void* g1, const void* be1,
    const void* b2, const void* g2, const void* be2,
    const int* __restrict__ flag,
    unsigned short* __restrict__ W1P, unsigned short* __restrict__ W2P,
    float* b1F, float* g1F, float* be1F, float* b2F, float* g2F, float* be2F) {
    int f = flag[0];
    if (blockIdx.x < 16) {
        int tid = blockIdx.x * 256 + threadIdx.x;       // 0..4095
        int lane = tid & 63, kk = (tid >> 6) & 3, jt = tid >> 8;
        int col = jt * 16 + (lane & 15);
        int k0 = kk * 32 + (lane >> 4) * 8;
        unsigned short v[8];
        #pragma unroll
        for (int j = 0; j < 8; ++j) v[j] = in_bf16(W1, (size_t)(k0 + j) * 256 + col, f);
        #pragma unroll
        for (int j = 0; j < 8; ++j) W1P[(size_t)tid * 8 + j] = v[j];
    } else if (blockIdx.x < 32) {
        int tid = (blockIdx.x - 16) * 256 + threadIdx.x; // 0..4095
        int lane = tid & 63, kk = (tid >> 6) & 7, jt = tid >> 9;
        int col = jt * 16 + (lane & 15);
        int k0 = kk * 32 + (lane >> 4) * 8;
        unsigned short v[8];
        #pragma unroll
        for (int j = 0; j < 8; ++j) v[j] = in_bf16(W2, (size_t)(k0 + j) * 128 + col, f);
        #pragma unroll
        for (int j = 0; j < 8; ++j) W2P[(size_t)tid * 8 + j] = v[j];
    } else {
        int t = threadIdx.x;
        b1F[t]  = in_f32(b1, t, f);
        g1F[t]  = in_f32(g1, t, f);
        be1F[t] = in_f32(be1, t, f);
        if (t < 128) {
            b2F[t]  = in_f32(b2, t, f);
            g2F[t]  = in_f32(g2, t, f);
            be2F[t] = in_f32(be2, t, f);
        }
    }
}

// ---------------- CSR build (bucketed, block-local slot allocation) ----------------
__global__ __launch_bounds__(256) void bucket_scatter_k(
    const int* __restrict__ src, const int* __restrict__ dst,
    int* __restrict__ bucket_cnt, unsigned int* __restrict__ bucket, int E, int nbk) {
    __shared__ int hist[NBK_MAX];
    __shared__ int basel[NBK_MAX];
    int t = threadIdx.x;
    int e0 = blockIdx.x * CHUNK;
    int e1 = min(e0 + CHUNK, E);

    for (int i = t; i < nbk; i += 256) hist[i] = 0;
    __syncthreads();
    for (int e = e0 + t; e < e1; e += 256) {
        int d = __builtin_nontemporal_load(&dst[e]);
        atomicAdd(&hist[d >> 7], 1);
    }
    __syncthreads();
    for (int i = t; i < nbk; i += 256) {
        int c = hist[i];
        basel[i] = c ? atomicAdd(&bucket_cnt[i], c) : 0;
        hist[i] = 0;
    }
    __syncthreads();
    for (int e = e0 + t; e < e1; e += 256) {
        int d = __builtin_nontemporal_load(&dst[e]);
        int s = __builtin_nontemporal_load(&src[e]);
        int b = d >> 7;
        int slot = basel[b] + atomicAdd(&hist[b], 1);
        if (slot < BCAP)
            bucket[(size_t)b * BCAP + slot] = ((unsigned int)(d & 127) << 16) | (unsigned int)s;
    }
}

// one block per bucket: LDS hist + scan -> cnt/offs/dinv, csr fill into the
// fixed per-bucket region [b*BCAP, ...) (no global scan needed), then xs for
// this bucket's 128 nodes: xs[n] = bf16(dinv[n] * embed[x_ids[n]])
__global__ __launch_bounds__(256) void bucket_fill_k(
    const unsigned int* __restrict__ bucket, const int* __restrict__ bucket_cnt,
    int* __restrict__ cnt, int* __restrict__ offs, float* __restrict__ dinv,
    unsigned short* __restrict__ csr,
    const int* __restrict__ x_ids, const void* __restrict__ embed,
    const int* __restrict__ flag, unsigned short* __restrict__ xs, int N) {
    __shared__ int cnts[128], excl[128], curl[128];
    __shared__ float dinvl[128];
    int t = threadIdx.x;
    int b = blockIdx.x;
    int base = b << 7;
    int nn = min(128, N - base);
    int total = min(bucket_cnt[b], BCAP);
    int cbase = b * BCAP;
    const unsigned int* bp = bucket + (size_t)b * BCAP;

    if (t < 128) cnts[t] = 0;
    __syncthreads();
    for (int i = t; i < total; i += 256)
        atomicAdd(&cnts[bp[i] >> 16], 1);
    __syncthreads();
    if (t < 128) excl[t] = cnts[t];
    __syncthreads();
    for (int o = 1; o < 128; o <<= 1) {
        int v = (t < 128 && t >= o) ? excl[t - o] : 0;
        __syncthreads();
        if (t < 128) excl[t] += v;
        __syncthreads();
    }
    if (t < nn) {
        int c = cnts[t];
        int ex = excl[t] - c;          // exclusive prefix
        int node = base + t;
        cnt[node] = c;
        offs[node] = cbase + ex;
        float dv = rsqrtf((float)(c + 1));
        dinv[node] = dv;
        dinvl[t] = dv;
        curl[t] = ex;
    }
    __syncthreads();
    for (int i = t; i < total; i += 256) {
        unsigned int e = bp[i];
        int d = e >> 16;
        int slot = atomicAdd(&curl[d], 1);
        csr[cbase + slot] = (unsigned short)(e & 0xffffu);
    }
    // xs for this bucket (uses dinvl; independent of csr writes)
    int f = flag[0];
    for (int i = t; i < nn * 16; i += 256) {
        int nl = i >> 4, c = i & 15;
        int n = base + nl;
        int id = x_ids[n];
        float dv = dinvl[nl];
        float v[8];
        if (f) {
            const float* er = (const float*)embed + (size_t)id * 128 + c * 8;
            float4 a = *(const float4*)er;
            float4 bb = *(const float4*)(er + 4);
            v[0]=a.x; v[1]=a.y; v[2]=a.z; v[3]=a.w;
            v[4]=bb.x; v[5]=bb.y; v[6]=bb.z; v[7]=bb.w;
        } else {
            uint4 u = *(const uint4*)((const unsigned short*)embed + (size_t)id * 128 + c * 8);
            cvt2(u.x, v[0], v[1]); cvt2(u.y, v[2], v[3]);
            cvt2(u.z, v[4], v[5]); cvt2(u.w, v[6], v[7]);
        }
        union { unsigned short s[8]; uint4 u; } o;
        #pragma unroll
        for (int j = 0; j < 8; ++j) o.s[j] = f2bf(v[j] * dv);
        *(uint4*)&xs[(size_t)n * 128 + c * 8] = o.u;
    }
}

// FUSED layer 1: per block of 64 nodes -- each wave gathers its own 16 rows
// (agg1s) into a padded LDS tile, then MFMA + bias + ReLU + LN epilogue.
// LDS is wave-local (wave w writes/reads only rows w*16..w*16+15): no barrier.
#define ROWP 136    // 128 + 8 ushort pad -> 2-way-free LDS banks
__global__ __launch_bounds__(256) void agg_gemm_ln1_k(
    const unsigned short* __restrict__ xs, const int* __restrict__ offs,
    const int* __restrict__ cnt, const unsigned short* __restrict__ csr,
    const unsigned short* __restrict__ W1P, const float* __restrict__ dinv,
    const float* __restrict__ b1, const float* __restrict__ g1,
    const float* __restrict__ be1, unsigned short* __restrict__ x1, int N)
{
    __shared__ unsigned short aggl[64 * ROWP];
    const int t = threadIdx.x;
    const int w = t >> 6;
    const int lane = t & 63;
    const int m = lane & 15;
    const int quad = lane >> 4;
    const int nb = blockIdx.x * 64;

    // gather phase: aggregate node nb+w*16+i into LDS row w*16+i
    for (int i = 0; i < 16; ++i) {
        int n = nb + w * 16 + i;
        float o0 = 0.f, o1 = 0.f;
        if (n < N) {
            float ax[8], ay[8];
            #pragma unroll
            for (int k = 0; k < 8; ++k) { ax[k] = 0.f; ay[k] = 0.f; }
            {
                unsigned int r = *(const unsigned int*)&xs[(size_t)n * 128 + lane * 2];
                cvt2(r, ax[0], ay[0]);   // self-loop term
            }
            int beg = offs[n];
            int end = beg + cnt[n];
            int j = beg;
            for (; j + 7 < end; j += 8) {
                unsigned int rr[8];
                #pragma unroll
                for (int k = 0; k < 8; ++k) {
                    int s = csr[j + k];
                    rr[k] = *(const unsigned int*)&xs[(size_t)s * 128 + lane * 2];
                }
                #pragma unroll
                for (int k = 0; k < 8; ++k) {
                    float v0, v1; cvt2(rr[k], v0, v1);
                    ax[k] += v0; ay[k] += v1;
                }
            }
            for (; j + 1 < end; j += 2) {
                int s0 = csr[j], s1 = csr[j + 1];
                unsigned int r0 = *(const unsigned int*)&xs[(size_t)s0 * 128 + lane * 2];
                unsigned int r1 = *(const unsigned int*)&xs[(size_t)s1 * 128 + lane * 2];
                float v0, v1; cvt2(r0, v0, v1); ax[0] += v0; ay[0] += v1;
                cvt2(r1, v0, v1); ax[1] += v0; ay[1] += v1;
            }
            if (j < end) {
                int s0 = csr[j];
                unsigned int r0 = *(const unsigned int*)&xs[(size_t)s0 * 128 + lane * 2];
                float v0, v1; cvt2(r0, v0, v1); ax[0] += v0; ay[0] += v1;
            }
            o0 = ((ax[0]+ax[1])+(ax[2]+ax[3])) + ((ax[4]+ax[5])+(ax[6]+ax[7]));
            o1 = ((ay[0]+ay[1])+(ay[2]+ay[3])) + ((ay[4]+ay[5])+(ay[6]+ay[7]));
        }
        unsigned int pk = (unsigned int)f2bf(o0) | ((unsigned int)f2bf(o1) << 16);
        *(unsigned int*)&aggl[(w * 16 + i) * ROWP + lane * 2] = pk;
    }

    // MFMA phase: A-fragments from this wave's own LDS rows
    bf16x8 a[4];
    #pragma unroll
    for (int kk = 0; kk < 4; ++kk)
        a[kk] = *(const bf16x8*)&aggl[(w * 16 + m) * ROWP + quad * 8 + kk * 32];

    f32x4 acc[16];
    #pragma unroll
    for (int jt = 0; jt < 16; ++jt) acc[jt] = (f32x4){0.f, 0.f, 0.f, 0.f};

    #pragma unroll
    for (int kk = 0; kk < 4; ++kk) {
        #pragma unroll
        for (int jt = 0; jt < 16; ++jt) {
            bf16x8 b = *(const bf16x8*)(W1P + ((size_t)(jt * 4 + kk) * 64 + lane) * 8);
            acc[jt] = __builtin_amdgcn_mfma_f32_16x16x32_bf16(a[kk], b, acc[jt], 0, 0, 0);
        }
    }

    float bcol[16], gcol[16], ecol[16];
    #pragma unroll
    for (int jt = 0; jt < 16; ++jt) {
        bcol[jt] = b1[jt * 16 + m];
        gcol[jt] = g1[jt * 16 + m];
        ecol[jt] = be1[jt * 16 + m];
    }
    int base = nb + w * 16 + quad * 4;
    float4 dv4 = *(const float4*)&dinv[base < N ? base : 0];
    float dvr[4] = {dv4.x, dv4.y, dv4.z, dv4.w};

    #pragma unroll
    for (int reg = 0; reg < 4; ++reg) {
        int row = base + reg;
        float v[16];
        float s = 0.f, q = 0.f;
        #pragma unroll
        for (int jt = 0; jt < 16; ++jt) {
            float x = fmaxf(fmaf(acc[jt][reg], dvr[reg], bcol[jt]), 0.0f);
            v[jt] = x;
            s += x; q += x * x;
        }
        #pragma unroll
        for (int off = 1; off < 16; off <<= 1) {
            s += __shfl_xor(s, off);
            q += __shfl_xor(q, off);
        }
        float mu = s * (1.0f / 256.0f);
        float var = fmaxf(q * (1.0f / 256.0f) - mu * mu, 0.0f);
        float rstd = rsqrtf(var + 1e-5f);
        if (row < N) {
            unsigned short* xp = x1 + (size_t)row * 256 + m;
            #pragma unroll
            for (int jt = 0; jt < 16; ++jt)
                xp[jt * 16] = f2bf(fmaf((v[jt] - mu) * rstd, gcol[jt], ecol[jt]));
        }
    }
}

// GEMM2 (MFMA): h2s[n][j] = bf16( dinv[n] * sum_k x1[n][k] * W2[k][j] )
__global__ __launch_bounds__(256) void gemm2_k(
    const unsigned short* __restrict__ x1, const unsigned short* __restrict__ W2P,
    const float* __restrict__ dinv, unsigned short* __restrict__ h2s, int N)
{
    const int t = threadIdx.x;
    const int w = t >> 6;
    const int lane = t & 63;
    const int m = lane & 15;
    const int quad = lane >> 4;
    const int nb = blockIdx.x * 64;

    int node_a = nb + w * 16 + m;
    int idn = node_a < N ? node_a : N - 1;

    const unsigned short* er = x1 + (size_t)idn * 256 + quad * 8;
    bf16x8 a[8];
    #pragma unroll
    for (int kk = 0; kk < 8; ++kk)
        a[kk] = *(const bf16x8*)(er + kk * 32);

    f32x4 acc[8];
    #pragma unroll
    for (int jt = 0; jt < 8; ++jt) acc[jt] = (f32x4){0.f, 0.f, 0.f, 0.f};

    #pragma unroll
    for (int kk = 0; kk < 8; ++kk) {
        #pragma unroll
        for (int jt = 0; jt < 8; ++jt) {
            bf16x8 b = *(const bf16x8*)(W2P + ((size_t)(jt * 8 + kk) * 64 + lane) * 8);
            acc[jt] = __builtin_amdgcn_mfma_f32_16x16x32_bf16(a[kk], b, acc[jt], 0, 0, 0);
        }
    }

    int base = nb + w * 16 + quad * 4;
    float4 dv4 = *(const float4*)&dinv[base < N ? base : 0];
    float dvr[4] = {dv4.x, dv4.y, dv4.z, dv4.w};
    #pragma unroll
    for (int reg = 0; reg < 4; ++reg) {
        int node_r = base + reg;
        if (node_r < N) {
            unsigned short* hp = h2s + (size_t)node_r * 128 + m;
            #pragma unroll
            for (int jt = 0; jt < 8; ++jt)
                hp[jt * 16] = f2bf(acc[jt][reg] * dvr[reg]);
        }
    }
}

// fused gather-aggregate + LN layer 2; persistent grid-stride waves, final store
__global__ __launch_bounds__(256) void agg_ln2_k(
    const unsigned short* __restrict__ h2s, const int* __restrict__ offs,
    const int* __restrict__ cnt, const unsigned short* __restrict__ csr,
    const float* __restrict__ dinv, const float* __restrict__ b2,
    const float* __restrict__ g2, const float* __restrict__ be2,
    const int* __restrict__ flag, void* __restrict__ out, int N)
{
    int lane = threadIdx.x & 63;
    int wid = blockIdx.x * 4 + (threadIdx.x >> 6);
    int f = flag[0];

    for (int n = wid; n < N; n += AGG_WAVES) {
        float ax[8], ay[8];
        #pragma unroll
        for (int i = 0; i < 8; ++i) { ax[i] = 0.f; ay[i] = 0.f; }
        {
            unsigned int r = *(const unsigned int*)&h2s[(size_t)n * 128 + lane * 2];
            cvt2(r, ax[0], ay[0]);
        }
        int beg = offs[n];
        int end = beg + cnt[n];
        int j = beg;
        for (; j + 7 < end; j += 8) {
            unsigned int rr[8];
            #pragma unroll
            for (int i = 0; i < 8; ++i) {
                int s = csr[j + i];
                rr[i] = *(const unsigned int*)&h2s[(size_t)s * 128 + lane * 2];
            }
            #pragma unroll
            for (int i = 0; i < 8; ++i) {
                float v0, v1; cvt2(rr[i], v0, v1);
                ax[i] += v0; ay[i] += v1;
            }
        }
        for (; j + 1 < end; j += 2) {
            int s0 = csr[j], s1 = csr[j + 1];
            unsigned int r0 = *(const unsigned int*)&h2s[(size_t)s0 * 128 + lane * 2];
            unsigned int r1 = *(const unsigned int*)&h2s[(size_t)s1 * 128 + lane * 2];
            float v0, v1; cvt2(r0, v0, v1); ax[0] += v0; ay[0] += v1;
            cvt2(r1, v0, v1); ax[1] += v0; ay[1] += v1;
        }
        if (j < end) {
            int s0 = csr[j];
            unsigned int r0 = *(const unsigned int*)&h2s[(size_t)s0 * 128 + lane * 2];
            float v0, v1; cvt2(r0, v0, v1); ax[0] += v0; ay[0] += v1;
        }
        float sum0 = ((ax[0]+ax[1])+(ax[2]+ax[3])) + ((ax[4]+ax[5])+(ax[6]+ax[7]));
        float sum1 = ((ay[0]+ay[1])+(ay[2]+ay[3])) + ((ay[4]+ay[5])+(ay[6]+ay[7]));
        float dv = dinv[n];
        float2 bv = *(const float2*)&b2[lane * 2];
        float x0 = fmaf(sum0, dv, bv.x);
        float x1 = fmaf(sum1, dv, bv.y);
        float s = x0 + x1;
        float q = x0*x0 + x1*x1;
        #pragma unroll
        for (int off = 32; off > 0; off >>= 1) {
            s += __shfl_xor(s, off);
            q += __shfl_xor(q, off);
        }
        float mu = s * (1.0f / 128.0f);
        float var = fmaxf(q * (1.0f / 128.0f) - mu * mu, 0.0f);
        float rstd = rsqrtf(var + 1e-5f);
        float2 gv = *(const float2*)&g2[lane * 2];
        float2 ev = *(const float2*)&be2[lane * 2];
        float o0 = fmaf((x0 - mu) * rstd, gv.x, ev.x);
        float o1 = fmaf((x1 - mu) * rstd, gv.y, ev.y);
        if (f) {
            *(float2*)&((float*)out)[(size_t)n * 128 + lane * 2] = make_float2(o0, o1);
        } else {
            unsigned int packed = (unsigned int)f2bf(o0) | ((unsigned int)f2bf(o1) << 16);
            *(unsigned int*)&((unsigned short*)out)[(size_t)n * 128 + lane * 2] = packed;
        }
    }
}

extern "C" void kernel_launch(void* const* d_in, const int* in_sizes, int n_in,
                              void* d_out, int out_size, void* d_ws, size_t ws_size,
                              hipStream_t stream) {
    const int N = in_sizes[0];
    const int E = in_sizes[1] / 2;
    const int nbk = (N + 127) >> 7;

    const int* x_ids = (const int*)d_in[0];
    const int* src = (const int*)d_in[1];
    const int* dst = src + E;
    const void* embed = d_in[2];
    const void* W1 = d_in[3];
    const void* b1 = d_in[4];
    const void* g1 = d_in[5];
    const void* be1 = d_in[6];
    const void* W2 = d_in[7];
    const void* b2 = d_in[8];
    const void* g2 = d_in[9];
    const void* be2 = d_in[10];

    char* w = (char*)d_ws;
    auto take = [&](size_t bytes) { char* p = w; w += (bytes + 255) & ~(size_t)255; return p; };
    int* flag             = (int*)take(4);
    unsigned short* W1P   = (unsigned short*)take(65536);
    unsigned short* W2P   = (unsigned short*)take(65536);
    float* b1F  = (float*)take(1024);
    float* g1F  = (float*)take(1024);
    float* be1F = (float*)take(1024);
    float* b2F  = (float*)take(512);
    float* g2F  = (float*)take(512);
    float* be2F = (float*)take(512);
    int* bucket_cnt = (int*)take((size_t)nbk * 4);
    unsigned int* bucket = (unsigned int*)take((size_t)nbk * BCAP * 4);
    int* cnt    = (int*)take((size_t)N * 4);
    int* offs   = (int*)take((size_t)N * 4);
    unsigned short* csr = (unsigned short*)take((size_t)nbk * BCAP * 2);
    float* dinv = (float*)take(((size_t)N + 64) * 4);
    unsigned short* xs  = (unsigned short*)take((size_t)N * 128 * 2);
    unsigned short* x1  = (unsigned short*)take((size_t)N * 256 * 2);
    unsigned short* h2s = xs;   // xs fully consumed by agg_gemm_ln1 before gemm2 writes h2s

    detect_k<<<1, 256, 0, stream>>>((const unsigned int*)embed, flag, bucket_cnt, nbk);
    pack_k  <<<33, 256, 0, stream>>>(W1, W2, b1, g1, be1, b2, g2, be2, flag,
                                     W1P, W2P, b1F, g1F, be1F, b2F, g2F, be2F);

    // CSR build (bucketed, block-local slot allocation; fixed-stride regions)
    bucket_scatter_k<<<(E + CHUNK - 1) / CHUNK, 256, 0, stream>>>(src, dst, bucket_cnt, bucket, E, nbk);
    bucket_fill_k   <<<nbk, 256, 0, stream>>>(bucket, bucket_cnt, cnt, offs, dinv, csr,
                                              x_ids, embed, flag, xs, N);

    // layer 1: fused gather-aggregate -> MFMA -> bias+ReLU+LN
    agg_gemm_ln1_k<<<(N + 63) / 64, 256, 0, stream>>>(xs, offs, cnt, csr, W1P, dinv,
                                                      b1F, g1F, be1F, x1, N);

    // layer 2: GEMM -> aggregate + LN (final store)
    gemm2_k   <<<(N + 63) / 64, 256, 0, stream>>>(x1, W2P, dinv, h2s, N);
    agg_ln2_k <<<AGG_WAVES / 4, 256, 0, stream>>>(h2s, offs, cnt, csr, dinv, b2F, g2F, be2F, flag, d_out, N);
}

// Round 12
// 255.714 us; speedup vs baseline: 1.1990x; 1.1990x over previous
//
#include <hip/hip_runtime.h>
#include <hip/hip_bf16.h>
#include <cstdint>
#include <cstddef>

typedef short bf16x8 __attribute__((ext_vector_type(8)));   // 8 bf16 (4 VGPRs)
typedef float f32x4 __attribute__((ext_vector_type(4)));    // MFMA C/D

#define BCAP 4096          // entries per bucket (mean ~2046 at N=50k,E=800k)
#define NBK_MAX 512        // max buckets (N<=65536 -> <=512)
#define CHUNK 8192         // edges per scatter block
#define AGG_WAVES 8192

__device__ __forceinline__ void cvt2(unsigned int u, float& lo, float& hi) {
    union { unsigned int i; float f; } a, b;
    a.i = u << 16;
    b.i = u & 0xffff0000u;
    lo = a.f; hi = b.f;
}
__device__ __forceinline__ float bf2f(unsigned short s) {
    union { unsigned int i; float f; } c; c.i = ((unsigned int)s) << 16;
    return c.f;
}
__device__ __forceinline__ unsigned short f2bf(float f) {
    union { float f; unsigned int i; } c; c.f = f;
    unsigned int x = c.i;
    unsigned int r = (x + 0x7fffu + ((x >> 16) & 1u)) >> 16;
    return (unsigned short)r;
}

// single block: zero flag + bucket counters, detect dtype from 16KB sample
__global__ __launch_bounds__(256) void detect_k(const unsigned int* __restrict__ emb,
                                                int* __restrict__ flag,
                                                int* __restrict__ bucket_cnt, int nbk) {
    __shared__ unsigned int red[256];
    int t = threadIdx.x;
    for (int i = t; i < nbk; i += 256) bucket_cnt[i] = 0;
    unsigned int m = 0;
    #pragma unroll
    for (int i = 0; i < 16; ++i) {
        unsigned int u = emb[t + 256 * i];
        unsigned int lo = (u << 16) & 0x7fffffffu;
        m = m > lo ? m : lo;
    }
    red[t] = m; __syncthreads();
    for (int s = 128; s > 0; s >>= 1) {
        if (t < s) red[t] = red[t] > red[t + s] ? red[t] : red[t + s];
        __syncthreads();
    }
    if (t == 0) flag[0] = (red[0] > 0x4B000000u) ? 1 : 0;   // > 2^23 => fp32
}

__device__ __forceinline__ unsigned short in_bf16(const void* p, size_t i, int f) {
    if (f) return f2bf(((const float*)p)[i]);
    return ((const unsigned short*)p)[i];
}
__device__ __forceinline__ float in_f32(const void* p, size_t i, int f) {
    if (f) return ((const float*)p)[i];
    return bf2f(((const unsigned short*)p)[i]);
}

// merged pack: blocks 0..15 W1 frags, 16..31 W2 frags, 32 LN/bias params
__global__ __launch_bounds__(256) void pack_k(
    const void* __restrict__ W1, const void* __restrict__ W2,
    const void* b1, const void* g1, const void* be1,
    const void* b2, const void* g2, const void* be2,
    const int* __restrict__ flag,
    unsigned short* __restrict__ W1P, unsigned short* __restrict__ W2P,
    float* b1F, float* g1F, float* be1F, float* b2F, float* g2F, float* be2F) {
    int f = flag[0];
    if (blockIdx.x < 16) {
        int tid = blockIdx.x * 256 + threadIdx.x;       // 0..4095
        int lane = tid & 63, kk = (tid >> 6) & 3, jt = tid >> 8;
        int col = jt * 16 + (lane & 15);
        int k0 = kk * 32 + (lane >> 4) * 8;
        unsigned short v[8];
        #pragma unroll
        for (int j = 0; j < 8; ++j) v[j] = in_bf16(W1, (size_t)(k0 + j) * 256 + col, f);
        #pragma unroll
        for (int j = 0; j < 8; ++j) W1P[(size_t)tid * 8 + j] = v[j];
    } else if (blockIdx.x < 32) {
        int tid = (blockIdx.x - 16) * 256 + threadIdx.x; // 0..4095
        int lane = tid & 63, kk = (tid >> 6) & 7, jt = tid >> 9;
        int col = jt * 16 + (lane & 15);
        int k0 = kk * 32 + (lane >> 4) * 8;
        unsigned short v[8];
        #pragma unroll
        for (int j = 0; j < 8; ++j) v[j] = in_bf16(W2, (size_t)(k0 + j) * 128 + col, f);
        #pragma unroll
        for (int j = 0; j < 8; ++j) W2P[(size_t)tid * 8 + j] = v[j];
    } else {
        int t = threadIdx.x;
        b1F[t]  = in_f32(b1, t, f);
        g1F[t]  = in_f32(g1, t, f);
        be1F[t] = in_f32(be1, t, f);
        if (t < 128) {
            b2F[t]  = in_f32(b2, t, f);
            g2F[t]  = in_f32(g2, t, f);
            be2F[t] = in_f32(be2, t, f);
        }
    }
}

// ---------------- CSR build (bucketed, block-local slot allocation) ----------------
__global__ __launch_bounds__(256) void bucket_scatter_k(
    const int* __restrict__ src, const int* __restrict__ dst,
    int* __restrict__ bucket_cnt, unsigned int* __restrict__ bucket, int E, int nbk) {
    __shared__ int hist[NBK_MAX];
    __shared__ int basel[NBK_MAX];
    int t = threadIdx.x;
    int e0 = blockIdx.x * CHUNK;
    int e1 = min(e0 + CHUNK, E);

    for (int i = t; i < nbk; i += 256) hist[i] = 0;
    __syncthreads();
    for (int e = e0 + t; e < e1; e += 256) {
        int d = __builtin_nontemporal_load(&dst[e]);
        atomicAdd(&hist[d >> 7], 1);
    }
    __syncthreads();
    for (int i = t; i < nbk; i += 256) {
        int c = hist[i];
        basel[i] = c ? atomicAdd(&bucket_cnt[i], c) : 0;
        hist[i] = 0;
    }
    __syncthreads();
    for (int e = e0 + t; e < e1; e += 256) {
        int d = __builtin_nontemporal_load(&dst[e]);
        int s = __builtin_nontemporal_load(&src[e]);
        int b = d >> 7;
        int slot = basel[b] + atomicAdd(&hist[b], 1);
        if (slot < BCAP)
            bucket[(size_t)b * BCAP + slot] = ((unsigned int)(d & 127) << 16) | (unsigned int)s;
    }
}

// one block per bucket: LDS hist + scan -> cnt/offs/dinv, csr fill into the
// fixed per-bucket region [b*BCAP, ...), then xs for this bucket's 128 nodes
__global__ __launch_bounds__(256) void bucket_fill_k(
    const unsigned int* __restrict__ bucket, const int* __restrict__ bucket_cnt,
    int* __restrict__ cnt, int* __restrict__ offs, float* __restrict__ dinv,
    unsigned short* __restrict__ csr,
    const int* __restrict__ x_ids, const void* __restrict__ embed,
    const int* __restrict__ flag, unsigned short* __restrict__ xs, int N) {
    __shared__ int cnts[128], excl[128], curl[128];
    __shared__ float dinvl[128];
    int t = threadIdx.x;
    int b = blockIdx.x;
    int base = b << 7;
    int nn = min(128, N - base);
    int total = min(bucket_cnt[b], BCAP);
    int cbase = b * BCAP;
    const unsigned int* bp = bucket + (size_t)b * BCAP;

    if (t < 128) cnts[t] = 0;
    __syncthreads();
    for (int i = t; i < total; i += 256)
        atomicAdd(&cnts[bp[i] >> 16], 1);
    __syncthreads();
    if (t < 128) excl[t] = cnts[t];
    __syncthreads();
    for (int o = 1; o < 128; o <<= 1) {
        int v = (t < 128 && t >= o) ? excl[t - o] : 0;
        __syncthreads();
        if (t < 128) excl[t] += v;
        __syncthreads();
    }
    if (t < nn) {
        int c = cnts[t];
        int ex = excl[t] - c;          // exclusive prefix
        int node = base + t;
        cnt[node] = c;
        offs[node] = cbase + ex;
        float dv = rsqrtf((float)(c + 1));
        dinv[node] = dv;
        dinvl[t] = dv;
        curl[t] = ex;
    }
    __syncthreads();
    for (int i = t; i < total; i += 256) {
        unsigned int e = bp[i];
        int d = e >> 16;
        int slot = atomicAdd(&curl[d], 1);
        csr[cbase + slot] = (unsigned short)(e & 0xffffu);
    }
    // xs for this bucket
    int f = flag[0];
    for (int i = t; i < nn * 16; i += 256) {
        int nl = i >> 4, c = i & 15;
        int n = base + nl;
        int id = x_ids[n];
        float dv = dinvl[nl];
        float v[8];
        if (f) {
            const float* er = (const float*)embed + (size_t)id * 128 + c * 8;
            float4 a = *(const float4*)er;
            float4 bb = *(const float4*)(er + 4);
            v[0]=a.x; v[1]=a.y; v[2]=a.z; v[3]=a.w;
            v[4]=bb.x; v[5]=bb.y; v[6]=bb.z; v[7]=bb.w;
        } else {
            uint4 u = *(const uint4*)((const unsigned short*)embed + (size_t)id * 128 + c * 8);
            cvt2(u.x, v[0], v[1]); cvt2(u.y, v[2], v[3]);
            cvt2(u.z, v[4], v[5]); cvt2(u.w, v[6], v[7]);
        }
        union { unsigned short s[8]; uint4 u; } o;
        #pragma unroll
        for (int j = 0; j < 8; ++j) o.s[j] = f2bf(v[j] * dv);
        *(uint4*)&xs[(size_t)n * 128 + c * 8] = o.u;
    }
}

// agg1s[d] = xs[d] + sum_{s in N(d)} xs[s]; persistent grid-stride waves
__global__ __launch_bounds__(256) void agg1_k(
    const unsigned short* __restrict__ xs, const int* __restrict__ offs,
    const int* __restrict__ cnt, const unsigned short* __restrict__ csr,
    unsigned short* __restrict__ agg1s, int N)
{
    int lane = threadIdx.x & 63;
    int wid = blockIdx.x * 4 + (threadIdx.x >> 6);

    for (int n = wid; n < N; n += AGG_WAVES) {
        float ax[8], ay[8];
        #pragma unroll
        for (int i = 0; i < 8; ++i) { ax[i] = 0.f; ay[i] = 0.f; }
        {
            unsigned int r = *(const unsigned int*)&xs[(size_t)n * 128 + lane * 2];
            cvt2(r, ax[0], ay[0]);
        }
        int beg = offs[n];
        int end = beg + cnt[n];
        int j = beg;
        for (; j + 7 < end; j += 8) {
            unsigned int rr[8];
            #pragma unroll
            for (int i = 0; i < 8; ++i) {
                int s = csr[j + i];
                rr[i] = *(const unsigned int*)&xs[(size_t)s * 128 + lane * 2];
            }
            #pragma unroll
            for (int i = 0; i < 8; ++i) {
                float v0, v1; cvt2(rr[i], v0, v1);
                ax[i] += v0; ay[i] += v1;
            }
        }
        for (; j + 1 < end; j += 2) {
            int s0 = csr[j], s1 = csr[j + 1];
            unsigned int r0 = *(const unsigned int*)&xs[(size_t)s0 * 128 + lane * 2];
            unsigned int r1 = *(const unsigned int*)&xs[(size_t)s1 * 128 + lane * 2];
            float v0, v1; cvt2(r0, v0, v1); ax[0] += v0; ay[0] += v1;
            cvt2(r1, v0, v1); ax[1] += v0; ay[1] += v1;
        }
        if (j < end) {
            int s0 = csr[j];
            unsigned int r0 = *(const unsigned int*)&xs[(size_t)s0 * 128 + lane * 2];
            float v0, v1; cvt2(r0, v0, v1); ax[0] += v0; ay[0] += v1;
        }
        float o0 = ((ax[0]+ax[1])+(ax[2]+ax[3])) + ((ax[4]+ax[5])+(ax[6]+ax[7]));
        float o1 = ((ay[0]+ay[1])+(ay[2]+ay[3])) + ((ay[4]+ay[5])+(ay[6]+ay[7]));
        unsigned int pk = (unsigned int)f2bf(o0) | ((unsigned int)f2bf(o1) << 16);
        *(unsigned int*)&agg1s[(size_t)n * 128 + lane * 2] = pk;
    }
}

// GEMM1 + bias + ReLU + LN fused: x1[n] = LN(relu(dinv[n]*(agg1s[n]@W1) + b1))
__global__ __launch_bounds__(256) void gemm_ln1_k(
    const unsigned short* __restrict__ agg1s, const unsigned short* __restrict__ W1P,
    const float* __restrict__ dinv, const float* __restrict__ b1,
    const float* __restrict__ g1, const float* __restrict__ be1,
    unsigned short* __restrict__ x1, int N)
{
    const int t = threadIdx.x;
    const int w = t >> 6;
    const int lane = t & 63;
    const int m = lane & 15;
    const int quad = lane >> 4;
    const int nb = blockIdx.x * 64;

    int node_a = nb + w * 16 + m;
    int idn = node_a < N ? node_a : N - 1;
    const unsigned short* er = agg1s + (size_t)idn * 128 + quad * 8;
    bf16x8 a[4];
    #pragma unroll
    for (int kk = 0; kk < 4; ++kk)
        a[kk] = *(const bf16x8*)(er + kk * 32);

    f32x4 acc[16];
    #pragma unroll
    for (int jt = 0; jt < 16; ++jt) acc[jt] = (f32x4){0.f, 0.f, 0.f, 0.f};

    #pragma unroll
    for (int kk = 0; kk < 4; ++kk) {
        #pragma unroll
        for (int jt = 0; jt < 16; ++jt) {
            bf16x8 b = *(const bf16x8*)(W1P + ((size_t)(jt * 4 + kk) * 64 + lane) * 8);
            acc[jt] = __builtin_amdgcn_mfma_f32_16x16x32_bf16(a[kk], b, acc[jt], 0, 0, 0);
        }
    }

    float bcol[16], gcol[16], ecol[16];
    #pragma unroll
    for (int jt = 0; jt < 16; ++jt) {
        bcol[jt] = b1[jt * 16 + m];
        gcol[jt] = g1[jt * 16 + m];
        ecol[jt] = be1[jt * 16 + m];
    }
    int base = nb + w * 16 + quad * 4;
    float4 dv4 = *(const float4*)&dinv[base < N ? base : 0];
    float dvr[4] = {dv4.x, dv4.y, dv4.z, dv4.w};

    #pragma unroll
    for (int reg = 0; reg < 4; ++reg) {
        int row = base + reg;
        float v[16];
        float s = 0.f, q = 0.f;
        #pragma unroll
        for (int jt = 0; jt < 16; ++jt) {
            float x = fmaxf(fmaf(acc[jt][reg], dvr[reg], bcol[jt]), 0.0f);
            v[jt] = x;
            s += x; q += x * x;
        }
        #pragma unroll
        for (int off = 1; off < 16; off <<= 1) {
            s += __shfl_xor(s, off);
            q += __shfl_xor(q, off);
        }
        float mu = s * (1.0f / 256.0f);
        float var = fmaxf(q * (1.0f / 256.0f) - mu * mu, 0.0f);
        float rstd = rsqrtf(var + 1e-5f);
        if (row < N) {
            unsigned short* xp = x1 + (size_t)row * 256 + m;
            #pragma unroll
            for (int jt = 0; jt < 16; ++jt)
                xp[jt * 16] = f2bf(fmaf((v[jt] - mu) * rstd, gcol[jt], ecol[jt]));
        }
    }
}

// GEMM2 (MFMA): h2s[n][j] = bf16( dinv[n] * sum_k x1[n][k] * W2[k][j] )
__global__ __launch_bounds__(256) void gemm2_k(
    const unsigned short* __restrict__ x1, const unsigned short* __restrict__ W2P,
    const float* __restrict__ dinv, unsigned short* __restrict__ h2s, int N)
{
    const int t = threadIdx.x;
    const int w = t >> 6;
    const int lane = t & 63;
    const int m = lane & 15;
    const int quad = lane >> 4;
    const int nb = blockIdx.x * 64;

    int node_a = nb + w * 16 + m;
    int idn = node_a < N ? node_a : N - 1;

    const unsigned short* er = x1 + (size_t)idn * 256 + quad * 8;
    bf16x8 a[8];
    #pragma unroll
    for (int kk = 0; kk < 8; ++kk)
        a[kk] = *(const bf16x8*)(er + kk * 32);

    f32x4 acc[8];
    #pragma unroll
    for (int jt = 0; jt < 8; ++jt) acc[jt] = (f32x4){0.f, 0.f, 0.f, 0.f};

    #pragma unroll
    for (int kk = 0; kk < 8; ++kk) {
        #pragma unroll
        for (int jt = 0; jt < 8; ++jt) {
            bf16x8 b = *(const bf16x8*)(W2P + ((size_t)(jt * 8 + kk) * 64 + lane) * 8);
            acc[jt] = __builtin_amdgcn_mfma_f32_16x16x32_bf16(a[kk], b, acc[jt], 0, 0, 0);
        }
    }

    int base = nb + w * 16 + quad * 4;
    float4 dv4 = *(const float4*)&dinv[base < N ? base : 0];
    float dvr[4] = {dv4.x, dv4.y, dv4.z, dv4.w};
    #pragma unroll
    for (int reg = 0; reg < 4; ++reg) {
        int node_r = base + reg;
        if (node_r < N) {
            unsigned short* hp = h2s + (size_t)node_r * 128 + m;
            #pragma unroll
            for (int jt = 0; jt < 8; ++jt)
                hp[jt * 16] = f2bf(acc[jt][reg] * dvr[reg]);
        }
    }
}

// fused gather-aggregate + LN layer 2; persistent grid-stride waves, final store
__global__ __launch_bounds__(256) void agg_ln2_k(
    const unsigned short* __restrict__ h2s, const int* __restrict__ offs,
    const int* __restrict__ cnt, const unsigned short* __restrict__ csr,
    const float* __restrict__ dinv, const float* __restrict__ b2,
    const float* __restrict__ g2, const float* __restrict__ be2,
    const int* __restrict__ flag, void* __restrict__ out, int N)
{
    int lane = threadIdx.x & 63;
    int wid = blockIdx.x * 4 + (threadIdx.x >> 6);
    int f = flag[0];

    for (int n = wid; n < N; n += AGG_WAVES) {
        float ax[8], ay[8];
        #pragma unroll
        for (int i = 0; i < 8; ++i) { ax[i] = 0.f; ay[i] = 0.f; }
        {
            unsigned int r = *(const unsigned int*)&h2s[(size_t)n * 128 + lane * 2];
            cvt2(r, ax[0], ay[0]);
        }
        int beg = offs[n];
        int end = beg + cnt[n];
        int j = beg;
        for (; j + 7 < end; j += 8) {
            unsigned int rr[8];
            #pragma unroll
            for (int i = 0; i < 8; ++i) {
                int s = csr[j + i];
                rr[i] = *(const unsigned int*)&h2s[(size_t)s * 128 + lane * 2];
            }
            #pragma unroll
            for (int i = 0; i < 8; ++i) {
                float v0, v1; cvt2(rr[i], v0, v1);
                ax[i] += v0; ay[i] += v1;
            }
        }
        for (; j + 1 < end; j += 2) {
            int s0 = csr[j], s1 = csr[j + 1];
            unsigned int r0 = *(const unsigned int*)&h2s[(size_t)s0 * 128 + lane * 2];
            unsigned int r1 = *(const unsigned int*)&h2s[(size_t)s1 * 128 + lane * 2];
            float v0, v1; cvt2(r0, v0, v1); ax[0] += v0; ay[0] += v1;
            cvt2(r1, v0, v1); ax[1] += v0; ay[1] += v1;
        }
        if (j < end) {
            int s0 = csr[j];
            unsigned int r0 = *(const unsigned int*)&h2s[(size_t)s0 * 128 + lane * 2];
            float v0, v1; cvt2(r0, v0, v1); ax[0] += v0; ay[0] += v1;
        }
        float sum0 = ((ax[0]+ax[1])+(ax[2]+ax[3])) + ((ax[4]+ax[5])+(ax[6]+ax[7]));
        float sum1 = ((ay[0]+ay[1])+(ay[2]+ay[3])) + ((ay[4]+ay[5])+(ay[6]+ay[7]));
        float dv = dinv[n];
        float2 bv = *(const float2*)&b2[lane * 2];
        float x0 = fmaf(sum0, dv, bv.x);
        float x1 = fmaf(sum1, dv, bv.y);
        float s = x0 + x1;
        float q = x0*x0 + x1*x1;
        #pragma unroll
        for (int off = 32; off > 0; off >>= 1) {
            s += __shfl_xor(s, off);
            q += __shfl_xor(q, off);
        }
        float mu = s * (1.0f / 128.0f);
        float var = fmaxf(q * (1.0f / 128.0f) - mu * mu, 0.0f);
        float rstd = rsqrtf(var + 1e-5f);
        float2 gv = *(const float2*)&g2[lane * 2];
        float2 ev = *(const float2*)&be2[lane * 2];
        float o0 = fmaf((x0 - mu) * rstd, gv.x, ev.x);
        float o1 = fmaf((x1 - mu) * rstd, gv.y, ev.y);
        if (f) {
            *(float2*)&((float*)out)[(size_t)n * 128 + lane * 2] = make_float2(o0, o1);
        } else {
            unsigned int packed = (unsigned int)f2bf(o0) | ((unsigned int)f2bf(o1) << 16);
            *(unsigned int*)&((unsigned short*)out)[(size_t)n * 128 + lane * 2] = packed;
        }
    }
}

extern "C" void kernel_launch(void* const* d_in, const int* in_sizes, int n_in,
                              void* d_out, int out_size, void* d_ws, size_t ws_size,
                              hipStream_t stream) {
    const int N = in_sizes[0];
    const int E = in_sizes[1] / 2;
    const int nbk = (N + 127) >> 7;

    const int* x_ids = (const int*)d_in[0];
    const int* src = (const int*)d_in[1];
    const int* dst = src + E;
    const void* embed = d_in[2];
    const void* W1 = d_in[3];
    const void* b1 = d_in[4];
    const void* g1 = d_in[5];
    const void* be1 = d_in[6];
    const void* W2 = d_in[7];
    const void* b2 = d_in[8];
    const void* g2 = d_in[9];
    const void* be2 = d_in[10];

    char* w = (char*)d_ws;
    auto take = [&](size_t bytes) { char* p = w; w += (bytes + 255) & ~(size_t)255; return p; };
    int* flag             = (int*)take(4);
    unsigned short* W1P   = (unsigned short*)take(65536);
    unsigned short* W2P   = (unsigned short*)take(65536);
    float* b1F  = (float*)take(1024);
    float* g1F  = (float*)take(1024);
    float* be1F = (float*)take(1024);
    float* b2F  = (float*)take(512);
    float* g2F  = (float*)take(512);
    float* be2F = (float*)take(512);
    int* bucket_cnt = (int*)take((size_t)nbk * 4);
    unsigned int* bucket = (unsigned int*)take((size_t)nbk * BCAP * 4);
    int* cnt    = (int*)take((size_t)N * 4);
    int* offs   = (int*)take((size_t)N * 4);
    unsigned short* csr = (unsigned short*)take((size_t)nbk * BCAP * 2);
    float* dinv = (float*)take(((size_t)N + 64) * 4);
    unsigned short* xs    = (unsigned short*)take((size_t)N * 128 * 2);
    unsigned short* agg1s = (unsigned short*)take((size_t)N * 128 * 2);
    unsigned short* x1    = (unsigned short*)take((size_t)N * 256 * 2);
    unsigned short* h2s   = agg1s;   // agg1s fully consumed by gemm_ln1 before gemm2 writes h2s

    detect_k<<<1, 256, 0, stream>>>((const unsigned int*)embed, flag, bucket_cnt, nbk);
    pack_k  <<<33, 256, 0, stream>>>(W1, W2, b1, g1, be1, b2, g2, be2, flag,
                                     W1P, W2P, b1F, g1F, be1F, b2F, g2F, be2F);

    // CSR build (bucketed, block-local slot allocation; fixed-stride regions)
    bucket_scatter_k<<<(E + CHUNK - 1) / CHUNK, 256, 0, stream>>>(src, dst, bucket_cnt, bucket, E, nbk);
    bucket_fill_k   <<<nbk, 256, 0, stream>>>(bucket, bucket_cnt, cnt, offs, dinv, csr,
                                              x_ids, embed, flag, xs, N);

    // layer 1: aggregate (128 feats) -> GEMM+bias+ReLU+LN fused epilogue
    agg1_k    <<<AGG_WAVES / 4, 256, 0, stream>>>(xs, offs, cnt, csr, agg1s, N);
    gemm_ln1_k<<<(N + 63) / 64, 256, 0, stream>>>(agg1s, W1P, dinv, b1F, g1F, be1F, x1, N);

    // layer 2: GEMM -> aggregate + LN (final store)
    gemm2_k   <<<(N + 63) / 64, 256, 0, stream>>>(x1, W2P, dinv, h2s, N);
    agg_ln2_k <<<AGG_WAVES / 4, 256, 0, stream>>>(h2s, offs, cnt, csr, dinv, b2F, g2F, be2F, flag, d_out, N);
}